// Round 4
// baseline (110.724 us; speedup 1.0000x reference)
//
#include <hip/hip_runtime.h>

// QueryAndGroup (PointNet++): ball query (R=0.2, nsample=32) + grouping.
// B=4, N=16384, NPOINT=2048, C=64, out = (B, 3+C, NPOINT, NSAMPLE) f32.
//
// R4 structure (2 kernels):
//   K1 prep (role-split grid, independent halves overlap):
//     blocks [0,1024):  transpose features (B,C,N) -> tf (B,N,C) in ws
//     blocks [1024,3072): ball query, ONE WAVE per query, 4 pts/lane
//       (3x float4, 1-deep prefetch), 256-pt windows, ballot-only ordered
//       append (no block barriers), early exit at 32 hits; padded idx -> ws.
//   K2 gather: pure streaming. Wave-per-query, lane=(s,h): 8 float4 row
//     gathers from tf + dense 128B-segment stores. No phase bubbles.
//
// d2 uses __f*_rn in the reference's association ((dx^2+dy^2)+dz^2): no FMA
// contraction -> bit-identical ball mask vs numpy (R1-R3: absmax 0.0).

namespace {
constexpr int kN   = 16384;
constexpr int kNP  = 2048;
constexpr int kC   = 64;
constexpr int kNS  = 32;
constexpr int kOC  = 3 + kC;   // 67
constexpr int kWin = 256;      // points per wave-window (4/lane)
}

__device__ __forceinline__ float d2_rn(float nx, float ny, float nz,
                                       float px, float py, float pz) {
    const float dx = __fsub_rn(nx, px);
    const float dy = __fsub_rn(ny, py);
    const float dz = __fsub_rn(nz, pz);
    return __fadd_rn(__fadd_rn(__fmul_rn(dx, dx), __fmul_rn(dy, dy)),
                     __fmul_rn(dz, dz));
}

// ---------- K1: transpose (blocks 0..1023) + ball query (blocks 1024..3071) --
__global__ __launch_bounds__(256) void prep_kernel(
    const float* __restrict__ xyz,      // (B, N, 3)
    const float* __restrict__ new_xyz,  // (B, NPOINT, 3)
    const float* __restrict__ feat,     // (B, C, N)
    float* __restrict__ tf,             // ws: (B, N, C)
    int*   __restrict__ idxbuf)         // ws: (B*NPOINT, NSAMPLE)
{
    __shared__ float tile[64][65];
    __shared__ int   sIdx[4][kNS];

    const int t = threadIdx.x;

    if (blockIdx.x < 1024) {
        // ---- transpose role ----
        const int b  = blockIdx.x >> 8;
        const int n0 = (blockIdx.x & 255) << 6;
        const float* fb = feat + (size_t)b * kC * kN;
        float* ob       = tf   + (size_t)b * kN * kC;
        const int q  = t >> 6;
        const int nn = t & 63;
        #pragma unroll
        for (int p = 0; p < 16; ++p) {
            const int c = p * 4 + q;
            tile[c][nn] = fb[(size_t)c * kN + n0 + nn];
        }
        __syncthreads();
        const int cc = t & 63;
        #pragma unroll
        for (int p = 0; p < 16; ++p) {
            const int n = p * 4 + q;
            ob[(size_t)(n0 + n) * kC + cc] = tile[cc][n];
        }
        return;
    }

    // ---- ball-query role: one wave per query ----
    const int w = t >> 6;
    const int l = t & 63;
    const int qid = (blockIdx.x - 1024) * 4 + w;   // 0..8191
    const int b   = qid >> 11;
    const int j   = qid & 2047;

    const float4* __restrict__ xv =
        reinterpret_cast<const float4*>(xyz + (size_t)b * kN * 3);
    const float* nxp = new_xyz + ((size_t)b * kNP + j) * 3;
    const float nx = nxp[0], ny = nxp[1], nz = nxp[2];
    const float R2 = 0.04f;

    int count = 0;
    float4 A0, A1, A2, B0, B1, B2;
    {
        const int o = 3 * l;                       // base=0 prefetch
        B0 = xv[o]; B1 = xv[o + 1]; B2 = xv[o + 2];
    }
    for (int base = 0; base < kN; base += kWin) {
        A0 = B0; A1 = B1; A2 = B2;
        if (base + kWin < kN) {
            const int o = ((base + kWin) >> 2) * 3 + 3 * l;
            B0 = xv[o]; B1 = xv[o + 1]; B2 = xv[o + 2];
        }
        const float d0  = d2_rn(nx, ny, nz, A0.x, A0.y, A0.z);
        const float d1  = d2_rn(nx, ny, nz, A0.w, A1.x, A1.y);
        const float d2v = d2_rn(nx, ny, nz, A1.z, A1.w, A2.x);
        const float d3  = d2_rn(nx, ny, nz, A2.y, A2.z, A2.w);
        const unsigned long long b0 = __ballot(d0  < R2);
        const unsigned long long b1 = __ballot(d1  < R2);
        const unsigned long long b2 = __ballot(d2v < R2);
        const unsigned long long b3 = __ballot(d3  < R2);

        const unsigned long long m = (1ull << l) - 1ull;
        int slot = count + (int)(__popcll(b0 & m) + __popcll(b1 & m) +
                                 __popcll(b2 & m) + __popcll(b3 & m));
        const int i0 = base + 4 * l;
        if (d0  < R2) { if (slot < kNS) sIdx[w][slot] = i0 + 0; ++slot; }
        if (d1  < R2) { if (slot < kNS) sIdx[w][slot] = i0 + 1; ++slot; }
        if (d2v < R2) { if (slot < kNS) sIdx[w][slot] = i0 + 2; ++slot; }
        if (d3  < R2) { if (slot < kNS) sIdx[w][slot] = i0 + 3; ++slot; }

        count += (int)(__popcll(b0) + __popcll(b1) +
                       __popcll(b2) + __popcll(b3));
        if (count >= kNS) break;   // wave-uniform
    }
    __builtin_amdgcn_wave_barrier();

    // fill rule: count==0 -> all 0; else pad tail with first in-ball index
    if (count == 0) {
        if (l < kNS) sIdx[w][l] = 0;
    } else if (count < kNS) {
        const int first = sIdx[w][0];
        __builtin_amdgcn_wave_barrier();
        if (l >= count && l < kNS) sIdx[w][l] = first;
    }
    __builtin_amdgcn_wave_barrier();

    if (l < kNS) idxbuf[(size_t)qid * kNS + l] = sIdx[w][l];
}

// ---------- K2: streaming gather + write (wave-per-query) ----------
__global__ __launch_bounds__(256) void gather_kernel(
    const float* __restrict__ xyz,      // (B, N, 3)
    const float* __restrict__ new_xyz,  // (B, NPOINT, 3)
    const float* __restrict__ tf,       // (B, N, C)
    const int*   __restrict__ idxbuf,   // (B*NPOINT, NSAMPLE)
    float* __restrict__ out)            // (B, 67, NPOINT, NSAMPLE)
{
    const int t = threadIdx.x;
    const int w = t >> 6;
    const int l = t & 63;

    // XCD-aware mapping: XCD pair {2b,2b+1} -> batch b (tf L2 locality).
    const int bid = blockIdx.x;          // 0..2047
    const int xcd = bid & 7;
    const int b   = xcd >> 1;
    const int jbl = ((xcd & 1) << 8) | (bid >> 3);   // 0..511
    const int j   = (jbl << 2) | w;      // 0..2047
    const int qid = (b << 11) | j;

    const int s = l & 31;
    const int h = l >> 5;
    const int id = idxbuf[(size_t)qid * kNS + s];

    const float* __restrict__ xb = xyz + (size_t)b * kN * 3;
    const float* nxp = new_xyz + ((size_t)b * kNP + j) * 3;
    const float nx = nxp[0], ny = nxp[1], nz = nxp[2];

    const size_t cs = (size_t)kNP * kNS;
    float* ob = out + ((size_t)b * kOC * kNP + j) * kNS + s;

    if (h == 0) {
        const float g0 = xb[(size_t)id * 3 + 0] - nx;
        const float g1 = xb[(size_t)id * 3 + 1] - ny;
        const float g2 = xb[(size_t)id * 3 + 2] - nz;
        ob[0 * cs] = g0;
        ob[1 * cs] = g1;
        ob[2 * cs] = g2;
    }

    const float* row = tf + ((size_t)b * kN + id) * kC;
    float* obf = ob + 3 * cs;
    #pragma unroll
    for (int it = 0; it < 8; ++it) {
        const int chunk = it * 2 + h;    // 0..15
        const float4 v = *reinterpret_cast<const float4*>(row + chunk * 4);
        const size_t c0 = (size_t)chunk * 4;
        obf[(c0 + 0) * cs] = v.x;
        obf[(c0 + 1) * cs] = v.y;
        obf[(c0 + 2) * cs] = v.z;
        obf[(c0 + 3) * cs] = v.w;
    }
}

// ---------- fallback (R1 kernel): direct gather from (C,N) ----------
__global__ __launch_bounds__(256) void qg_direct(
    const float* __restrict__ xyz, const float* __restrict__ new_xyz,
    const float* __restrict__ feat, float* __restrict__ out)
{
    __shared__ int sIdx[4][kNS];
    const int wave = threadIdx.x >> 6;
    const int lane = threadIdx.x & 63;
    const int bid  = blockIdx.x;
    const int xcd  = bid & 7;
    const int b    = xcd >> 1;
    const int jblk = ((xcd & 1) << 8) | (bid >> 3);
    const int j    = (jblk << 2) | wave;

    const float* __restrict__ xb = xyz + (size_t)b * kN * 3;
    const float* nxp = new_xyz + ((size_t)b * kNP + j) * 3;
    const float nx = nxp[0], ny = nxp[1], nz = nxp[2];
    const float R2 = 0.04f;

    int count = 0;
    for (int base = 0; base < kN; base += 64) {
        const int i = base + lane;
        const float d2 = d2_rn(nx, ny, nz, xb[(size_t)i * 3 + 0],
                               xb[(size_t)i * 3 + 1], xb[(size_t)i * 3 + 2]);
        const bool in = d2 < R2;
        const unsigned long long bal = __ballot(in);
        const int pre  = (int)__popcll(bal & ((1ull << lane) - 1ull));
        const int slot = count + pre;
        if (in && slot < kNS) sIdx[wave][slot] = i;
        count += (int)__popcll(bal);
        if (count >= kNS) break;
    }
    __builtin_amdgcn_wave_barrier();
    if (count == 0) {
        if (lane < kNS) sIdx[wave][lane] = 0;
    } else if (count < kNS) {
        const int first = sIdx[wave][0];
        __builtin_amdgcn_wave_barrier();
        if (lane >= count && lane < kNS) sIdx[wave][lane] = first;
    }
    __builtin_amdgcn_wave_barrier();

    const int s    = lane & 31;
    const int half = lane >> 5;
    const int id   = sIdx[wave][s];
    const float g0 = xb[(size_t)id * 3 + 0] - nx;
    const float g1 = xb[(size_t)id * 3 + 1] - ny;
    const float g2 = xb[(size_t)id * 3 + 2] - nz;
    const size_t cs = (size_t)kNP * kNS;
    float* ob = out + (((size_t)b * kOC) * kNP + j) * kNS + s;
    const float* fb = feat + ((size_t)b * kC) * kN + id;
    #pragma unroll
    for (int cb = 0; cb < kOC; cb += 2) {
        const int c = cb + half;
        if (c < kOC) {
            float v;
            if (c < 3) v = (c == 0) ? g0 : ((c == 1) ? g1 : g2);
            else       v = fb[(size_t)(c - 3) * kN];
            ob[(size_t)c * cs] = v;
        }
    }
}

extern "C" void kernel_launch(void* const* d_in, const int* in_sizes, int n_in,
                              void* d_out, int out_size, void* d_ws, size_t ws_size,
                              hipStream_t stream) {
    const float* xyz     = (const float*)d_in[0];
    const float* new_xyz = (const float*)d_in[1];
    const float* feat    = (const float*)d_in[2];
    float* out           = (float*)d_out;

    const size_t tf_bytes  = (size_t)4 * kN * kC * sizeof(float);   // 16.8 MB
    const size_t idx_bytes = (size_t)4 * kNP * kNS * sizeof(int);   // 1 MB
    if (ws_size >= tf_bytes + idx_bytes) {
        float* tf   = (float*)d_ws;
        int* idxbuf = (int*)((char*)d_ws + tf_bytes);
        // K1: 1024 transpose blocks + 2048 ball-query blocks (overlapped).
        prep_kernel  <<<dim3(3072), dim3(256), 0, stream>>>(
            xyz, new_xyz, feat, tf, idxbuf);
        // K2: pure streaming gather/write.
        gather_kernel<<<dim3(2048), dim3(256), 0, stream>>>(
            xyz, new_xyz, tf, idxbuf, out);
    } else {
        qg_direct<<<dim3(2048), dim3(256), 0, stream>>>(xyz, new_xyz, feat, out);
    }
}

// Round 5
// 106.752 us; speedup vs baseline: 1.0372x; 1.0372x over previous
//
#include <hip/hip_runtime.h>

// QueryAndGroup (PointNet++): ball query (R=0.2, nsample=32) + grouping.
// B=4, N=16384, NPOINT=2048, C=64, out = (B, 3+C, NPOINT, NSAMPLE) f32.
//
// R5 structure (2 kernels):
//   K1 tr_kernel: transpose features (B,C,N) -> tf (B,N,C) in ws.
//     Nontemporal loads (feat is read exactly once -> don't pollute L2).
//   K2 qg_fused: ONE WAVE per query, fully wave-independent (no block
//     barriers). Phase 1: ball query, 4 pts/lane (3x float4, 1-deep
//     prefetch), 256-pt windows, ballot-only ordered append, early exit.
//     Phase 2: immediately gather this query (lane=(s,h): 8 float4 row
//     reads from tf) and write with NONTEMPORAL stores (70 MB stream is
//     never re-read; keeps xyz+tf resident in L2 for other waves).
//     Straggler queries' gathers land late while other waves keep the
//     store pipe busy -> bq tail hidden under the write stream.
//
// d2 uses __f*_rn in the reference's association ((dx^2+dy^2)+dz^2): no FMA
// contraction -> bit-identical ball mask vs numpy (R1-R4: absmax 0.0).

namespace {
constexpr int kN   = 16384;
constexpr int kNP  = 2048;
constexpr int kC   = 64;
constexpr int kNS  = 32;
constexpr int kOC  = 3 + kC;   // 67
constexpr int kWin = 256;      // points per wave-window (4/lane)
}

__device__ __forceinline__ float d2_rn(float nx, float ny, float nz,
                                       float px, float py, float pz) {
    const float dx = __fsub_rn(nx, px);
    const float dy = __fsub_rn(ny, py);
    const float dz = __fsub_rn(nz, pz);
    return __fadd_rn(__fadd_rn(__fmul_rn(dx, dx), __fmul_rn(dy, dy)),
                     __fmul_rn(dz, dz));
}

// ---------- K1: feature transpose (B,C,N) -> (B,N,C), nt loads ----------
__global__ __launch_bounds__(256) void tr_kernel(
    const float* __restrict__ feat, float* __restrict__ tf)
{
    __shared__ float tile[64][65];
    const int b  = blockIdx.x >> 8;
    const int n0 = (blockIdx.x & 255) << 6;
    const float* fb = feat + (size_t)b * kC * kN;
    float* ob       = tf   + (size_t)b * kN * kC;
    const int t  = threadIdx.x;
    const int q  = t >> 6;
    const int nn = t & 63;
    #pragma unroll
    for (int p = 0; p < 16; ++p) {
        const int c = p * 4 + q;
        tile[c][nn] = __builtin_nontemporal_load(&fb[(size_t)c * kN + n0 + nn]);
    }
    __syncthreads();
    const int cc = t & 63;
    #pragma unroll
    for (int p = 0; p < 16; ++p) {
        const int n = p * 4 + q;
        ob[(size_t)(n0 + n) * kC + cc] = tile[cc][n];
    }
}

// ---------- K2: fused per-wave ball query + gather, nt stores ----------
__global__ __launch_bounds__(256) void qg_fused(
    const float* __restrict__ xyz,      // (B, N, 3)
    const float* __restrict__ new_xyz,  // (B, NPOINT, 3)
    const float* __restrict__ tf,       // (B, N, C)
    float* __restrict__ out)            // (B, 67, NPOINT, NSAMPLE)
{
    __shared__ int sIdx[4][kNS];
    const int t = threadIdx.x;
    const int w = t >> 6;
    const int l = t & 63;

    // XCD-aware mapping: XCD pair {2b,2b+1} -> batch b (xyz/tf L2 locality).
    const int bid = blockIdx.x;          // 0..2047
    const int xcd = bid & 7;
    const int b   = xcd >> 1;
    const int jbl = ((xcd & 1) << 8) | (bid >> 3);   // 0..511
    const int j   = (jbl << 2) | w;      // 0..2047

    const float* __restrict__ xb = xyz + (size_t)b * kN * 3;
    const float4* __restrict__ xv = reinterpret_cast<const float4*>(xb);
    const float* nxp = new_xyz + ((size_t)b * kNP + j) * 3;
    const float nx = nxp[0], ny = nxp[1], nz = nxp[2];
    const float R2 = 0.04f;

    // ---- phase 1: ball query (wave-private, ballot-only, no barriers) ----
    int count = 0;
    float4 A0, A1, A2, B0, B1, B2;
    {
        const int o = 3 * l;                       // base=0 prefetch
        B0 = xv[o]; B1 = xv[o + 1]; B2 = xv[o + 2];
    }
    for (int base = 0; base < kN; base += kWin) {
        A0 = B0; A1 = B1; A2 = B2;
        if (base + kWin < kN) {
            const int o = ((base + kWin) >> 2) * 3 + 3 * l;
            B0 = xv[o]; B1 = xv[o + 1]; B2 = xv[o + 2];
        }
        const float d0  = d2_rn(nx, ny, nz, A0.x, A0.y, A0.z);
        const float d1  = d2_rn(nx, ny, nz, A0.w, A1.x, A1.y);
        const float d2v = d2_rn(nx, ny, nz, A1.z, A1.w, A2.x);
        const float d3  = d2_rn(nx, ny, nz, A2.y, A2.z, A2.w);
        const unsigned long long b0 = __ballot(d0  < R2);
        const unsigned long long b1 = __ballot(d1  < R2);
        const unsigned long long b2 = __ballot(d2v < R2);
        const unsigned long long b3 = __ballot(d3  < R2);

        const unsigned long long m = (1ull << l) - 1ull;
        int slot = count + (int)(__popcll(b0 & m) + __popcll(b1 & m) +
                                 __popcll(b2 & m) + __popcll(b3 & m));
        const int i0 = base + 4 * l;
        if (d0  < R2) { if (slot < kNS) sIdx[w][slot] = i0 + 0; ++slot; }
        if (d1  < R2) { if (slot < kNS) sIdx[w][slot] = i0 + 1; ++slot; }
        if (d2v < R2) { if (slot < kNS) sIdx[w][slot] = i0 + 2; ++slot; }
        if (d3  < R2) { if (slot < kNS) sIdx[w][slot] = i0 + 3; ++slot; }

        count += (int)(__popcll(b0) + __popcll(b1) +
                       __popcll(b2) + __popcll(b3));
        if (count >= kNS) break;   // wave-uniform
    }
    __builtin_amdgcn_wave_barrier();

    // fill rule: count==0 -> all 0; else pad tail with first in-ball index
    if (count == 0) {
        if (l < kNS) sIdx[w][l] = 0;
    } else if (count < kNS) {
        const int first = sIdx[w][0];
        __builtin_amdgcn_wave_barrier();
        if (l >= count && l < kNS) sIdx[w][l] = first;
    }
    __builtin_amdgcn_wave_barrier();

    // ---- phase 2: gather + nontemporal write ----
    const int s = l & 31;
    const int h = l >> 5;
    const int id = sIdx[w][s];

    const size_t cs = (size_t)kNP * kNS;
    float* ob = out + ((size_t)b * kOC * kNP + j) * kNS + s;

    if (h == 0) {
        const float g0 = xb[(size_t)id * 3 + 0] - nx;
        const float g1 = xb[(size_t)id * 3 + 1] - ny;
        const float g2 = xb[(size_t)id * 3 + 2] - nz;
        __builtin_nontemporal_store(g0, &ob[0 * cs]);
        __builtin_nontemporal_store(g1, &ob[1 * cs]);
        __builtin_nontemporal_store(g2, &ob[2 * cs]);
    }

    const float* row = tf + ((size_t)b * kN + id) * kC;
    float* obf = ob + 3 * cs;
    #pragma unroll
    for (int it = 0; it < 8; ++it) {
        const int chunk = it * 2 + h;    // 0..15
        const float4 v = *reinterpret_cast<const float4*>(row + chunk * 4);
        const size_t c0 = (size_t)chunk * 4;
        __builtin_nontemporal_store(v.x, &obf[(c0 + 0) * cs]);
        __builtin_nontemporal_store(v.y, &obf[(c0 + 1) * cs]);
        __builtin_nontemporal_store(v.z, &obf[(c0 + 2) * cs]);
        __builtin_nontemporal_store(v.w, &obf[(c0 + 3) * cs]);
    }
}

// ---------- fallback (R1 kernel): direct gather from (C,N) ----------
__global__ __launch_bounds__(256) void qg_direct(
    const float* __restrict__ xyz, const float* __restrict__ new_xyz,
    const float* __restrict__ feat, float* __restrict__ out)
{
    __shared__ int sIdx[4][kNS];
    const int wave = threadIdx.x >> 6;
    const int lane = threadIdx.x & 63;
    const int bid  = blockIdx.x;
    const int xcd  = bid & 7;
    const int b    = xcd >> 1;
    const int jblk = ((xcd & 1) << 8) | (bid >> 3);
    const int j    = (jblk << 2) | wave;

    const float* __restrict__ xb = xyz + (size_t)b * kN * 3;
    const float* nxp = new_xyz + ((size_t)b * kNP + j) * 3;
    const float nx = nxp[0], ny = nxp[1], nz = nxp[2];
    const float R2 = 0.04f;

    int count = 0;
    for (int base = 0; base < kN; base += 64) {
        const int i = base + lane;
        const float d2 = d2_rn(nx, ny, nz, xb[(size_t)i * 3 + 0],
                               xb[(size_t)i * 3 + 1], xb[(size_t)i * 3 + 2]);
        const bool in = d2 < R2;
        const unsigned long long bal = __ballot(in);
        const int pre  = (int)__popcll(bal & ((1ull << lane) - 1ull));
        const int slot = count + pre;
        if (in && slot < kNS) sIdx[wave][slot] = i;
        count += (int)__popcll(bal);
        if (count >= kNS) break;
    }
    __builtin_amdgcn_wave_barrier();
    if (count == 0) {
        if (lane < kNS) sIdx[wave][lane] = 0;
    } else if (count < kNS) {
        const int first = sIdx[wave][0];
        __builtin_amdgcn_wave_barrier();
        if (lane >= count && lane < kNS) sIdx[wave][lane] = first;
    }
    __builtin_amdgcn_wave_barrier();

    const int s    = lane & 31;
    const int half = lane >> 5;
    const int id   = sIdx[wave][s];
    const float g0 = xb[(size_t)id * 3 + 0] - nx;
    const float g1 = xb[(size_t)id * 3 + 1] - ny;
    const float g2 = xb[(size_t)id * 3 + 2] - nz;
    const size_t cs = (size_t)kNP * kNS;
    float* ob = out + (((size_t)b * kOC) * kNP + j) * kNS + s;
    const float* fb = feat + ((size_t)b * kC) * kN + id;
    #pragma unroll
    for (int cb = 0; cb < kOC; cb += 2) {
        const int c = cb + half;
        if (c < kOC) {
            float v;
            if (c < 3) v = (c == 0) ? g0 : ((c == 1) ? g1 : g2);
            else       v = fb[(size_t)(c - 3) * kN];
            ob[(size_t)c * cs] = v;
        }
    }
}

extern "C" void kernel_launch(void* const* d_in, const int* in_sizes, int n_in,
                              void* d_out, int out_size, void* d_ws, size_t ws_size,
                              hipStream_t stream) {
    const float* xyz     = (const float*)d_in[0];
    const float* new_xyz = (const float*)d_in[1];
    const float* feat    = (const float*)d_in[2];
    float* out           = (float*)d_out;

    const size_t tf_bytes = (size_t)4 * kN * kC * sizeof(float);   // 16.8 MB
    if (ws_size >= tf_bytes) {
        float* tf = (float*)d_ws;
        tr_kernel<<<dim3(1024), dim3(256), 0, stream>>>(feat, tf);
        qg_fused <<<dim3(2048), dim3(256), 0, stream>>>(xyz, new_xyz, tf, out);
    } else {
        qg_direct<<<dim3(2048), dim3(256), 0, stream>>>(xyz, new_xyz, feat, out);
    }
}